// Round 9
// baseline (3091.180 us; speedup 1.0000x reference)
//
#include <hip/hip_runtime.h>

#define TT 1024
#define BB 256
#define HH 512
#define G4 2048
#define NG 32   // sample groups
#define SG 8    // samples per group
#define NJ 16   // wgs (j-slices) per group-pair cohort
#define RW 128  // rows per slice = 4 gates * 32 j
#define JW 32   // j per slice
#define FS 32   // flag stride (ints)

typedef _Float16 half2v __attribute__((ext_vector_type(2)));
typedef _Float16 half8  __attribute__((ext_vector_type(8)));
typedef __fp16   fp16x2 __attribute__((ext_vector_type(2)));
typedef float    f32x4  __attribute__((ext_vector_type(4)));
typedef unsigned int uint;
typedef unsigned long long u64t;

union U32H  { uint u; half2v h; fp16x2 g; };
union U128H { uint4 u; half8 h; };
union U64F  { u64t u; float f[2]; };

// ---------------- prep: fp16 W repack into MFMA A-fragments ----------------
// Row order inside a wave's 16-row tile: m = jjq*4 + gate  (jj-major, gate-minor)
// so a lane's 4 D-regs are the i,f,g,o of ONE jj.
// idx = (((jg*8 + w)*16 + kk)*64 + l)*4 + d :
//   m = l&15 -> gate = m&3, jjq = m>>2 ; grow = gate*512 + jg*32 + w*4 + jjq
//   k = kk*32 + ((l>>4)&3)*8 + 2d (+1)
__global__ __launch_bounds__(256) void prep_k(
    const float* __restrict__ Whh, const float* __restrict__ fcW,
    const float* __restrict__ bih, const float* __restrict__ bhh,
    uint* __restrict__ Wpk16, float* __restrict__ fcWT, float* __restrict__ bsum,
    float* __restrict__ hbuf, int* __restrict__ flags)
{
    int n  = blockDim.x * gridDim.x;
    int i0 = blockIdx.x * blockDim.x + threadIdx.x;
    for (int i = i0; i < NJ * 8 * 16 * 64 * 4; i += n) {
        int d  = i & 3;
        int l  = (i >> 2) & 63;
        int kk = (i >> 8) & 15;
        int w  = (i >> 12) & 7;
        int jg = (i >> 15) & 15;
        int m    = l & 15;
        int gate = m & 3, jjq = m >> 2;
        int grow = gate * HH + jg * JW + w * 4 + jjq;
        int k    = kk * 32 + ((l >> 4) & 3) * 8 + 2 * d;
        half2v p;
        p.x = (_Float16)Whh[grow * HH + k];
        p.y = (_Float16)Whh[grow * HH + k + 1];
        U32H x; x.h = p;
        Wpk16[i] = x.u;
    }
    for (int i = i0; i < HH * TT; i += n) {
        int k = i >> 10, t = i & (TT - 1);
        fcWT[i] = fcW[t * HH + k];
    }
    for (int i = i0; i < G4; i += n) bsum[i] = bih[i] + bhh[i];
    for (int i = i0; i < 2 * BB * HH; i += n) hbuf[i] = 0.f;
    for (int i = i0; i < NG * NJ * FS; i += n) flags[i] = 0;
}

// ---------------- lengths ----------------
__global__ __launch_bounds__(256) void lens_k(const float* __restrict__ traj,
                                              int* __restrict__ len)
{
    int b = blockIdx.x;
    int cnt = 0;
    for (int i = threadIdx.x; i < TT; i += 256)
        cnt += (traj[b * TT + i] != -1.0f) ? 1 : 0;
    for (int o = 32; o > 0; o >>= 1) cnt += __shfl_down(cnt, o, 64);
    __shared__ int s4[4];
    if ((threadIdx.x & 63) == 0) s4[threadIdx.x >> 6] = cnt;
    __syncthreads();
    if (threadIdx.x == 0) len[b] = s4[0] + s4[1] + s4[2] + s4[3];
}

// ---------------- sort by length (descending), group maxes ----------------
__global__ __launch_bounds__(256) void sort_k(const int* __restrict__ len,
                                              int* __restrict__ perm,
                                              int* __restrict__ glen)
{
    __shared__ int L[256];
    __shared__ int P[256];
    int tid = threadIdx.x;
    L[tid] = len[tid];
    __syncthreads();
    int l = L[tid], r = 0;
    for (int b = 0; b < 256; ++b) {
        int lb = L[b];
        r += (lb > l) || (lb == l && b < tid);
    }
    P[r] = tid;
    __syncthreads();
    perm[tid] = P[tid];
    if (tid < NG) glen[tid] = L[P[tid * SG]];
}

// ---------------- helpers ----------------
__device__ __forceinline__ void wait_flags(const int* __restrict__ flg, int target, int tid)
{
    int lane = tid & 63;
    while (true) {
        int v = target;
        if (lane < NJ)
            v = __hip_atomic_load(&flg[lane * FS], __ATOMIC_RELAXED, __HIP_MEMORY_SCOPE_AGENT);
        if (__all(v >= target)) break;
        __builtin_amdgcn_s_sleep(1);
    }
}

// ---------------- persistent LSTM: merged-pair MFMA, in-lane gates ---------
// grid 256 = 16 slots x 16 j-slices. Slot p serves groups gA=p (cols 0-7)
// and gB=31-p (cols 8-15) in the SAME MFMA pass. One barrier pair, one flag,
// one wait per step for both groups.
__global__ __launch_bounds__(512, 2) void lstm_persist(
    const float* __restrict__ traj, const float* __restrict__ Wih,
    const uint* __restrict__ Wpk16, const float* __restrict__ bsum,
    float* __restrict__ hbuf,                 // [2][BB][HH]
    const int* __restrict__ perm, const int* __restrict__ glen,
    int* __restrict__ flags)
{
    // one big genuinely-used LDS array (90KB) -> exactly 1 wg/CU
    __shared__ __align__(16) float smem[23040];
    __shared__ float xsm[16], mkm[16];
    __shared__ int   osm[16];
    __shared__ float wih_s[RW], bsum_s[RW];

    uint* const hs16 = (uint*)smem;   // 16 samples x 256 dw (swizzled halves)

    const int wg   = blockIdx.x;
    const int slot = wg & 15;
    const int jg   = wg >> 4;
    const int tid  = threadIdx.x;
    const int gA = slot, gB = 31 - slot;   // glen[gA] >= glen[gB]

    if (tid < 16)
        osm[tid] = perm[(tid < 8) ? (gA * SG + tid) : (gB * SG + tid - 8)];
    if (tid < RW) {
        int m = tid & 15;
        int grow = (m & 3) * HH + jg * JW + (tid >> 4) * 4 + (m >> 2);
        wih_s[tid]  = Wih[grow];
        bsum_s[tid] = bsum[grow];
    }
    const int glenA = glen[gA];

    // W A-fragments -> registers: 16 x half8, coalesced per kk
    half8 wf[16];
    {
        const int w = tid >> 6, l = tid & 63;
        const uint4* wp = (const uint4*)Wpk16;
        const int base = (jg * 8 + w) * 1024 + l;
        #pragma unroll
        for (int kk = 0; kk < 16; ++kk) {
            U128H u; u.u = wp[base + kk * 64];
            wf[kk] = u.h;
        }
    }

    // lane roles
    const int w  = tid >> 6;       // wave: rows for jj = w*4 .. w*4+3
    const int l  = tid & 63;
    const int sm = l & 15;         // MFMA column = sample slot (A:0-7, B:8-15)
    const int ks = (l >> 4) & 3;   // D row block: m = ks*4 + r
    const int jj = w * 4 + ks;     // this lane's hidden index within the slice
    const int sslot = (sm < 8) ? (gA * SG + sm) : (gB * SG + sm - 8);

    float creg = 0.f, hreg = 0.f;  // this lane's (jj, sample) state
    float pf[16];                  // staged h(t): [0-7]=sample tid>>6, [8-15]=+8
    #pragma unroll
    for (int q = 0; q < 16; ++q) pf[q] = 0.f;   // h(0) = 0

    int* const flg = flags + slot * NJ * FS;
    __syncthreads();

    for (int t = 0; t < glenA; ++t) {
        // ---- stage h(t) -> LDS (fp16 pairs, XOR-swizzled), both halves ----
        {
            int s = tid >> 6;
            int swz = (s & 7) << 2;
            #pragma unroll
            for (int q = 0; q < 4; ++q) {
                int k2 = q * 64 + l;
                U32H a, b;
                a.g = __builtin_amdgcn_cvt_pkrtz(pf[2 * q], pf[2 * q + 1]);
                b.g = __builtin_amdgcn_cvt_pkrtz(pf[8 + 2 * q], pf[9 + 2 * q]);
                hs16[s * 256 + (k2 ^ swz)]       = a.u;
                hs16[(s + 8) * 256 + (k2 ^ swz)] = b.u;
            }
        }
        if (tid < 16) {
            float v = traj[(size_t)osm[tid] * TT + t];
            xsm[tid] = v;
            mkm[tid] = (v != -1.0f) ? 1.f : 0.f;
        }
        __syncthreads();

        // ---- MFMA: 16 rows x 16 sample-columns, K=512, 2 acc chains ----
        f32x4 acc0 = {0.f, 0.f, 0.f, 0.f}, acc1 = {0.f, 0.f, 0.f, 0.f};
        {
            const int smswz = (sm & 7) << 2;
            const int bbase = sm * 256;
            #pragma unroll
            for (int kk = 0; kk < 16; kk += 2) {
                U128H b0, b1;
                b0.u = *(const uint4*)&hs16[bbase + ((kk * 16 + ks * 4) ^ smswz)];
                b1.u = *(const uint4*)&hs16[bbase + (((kk + 1) * 16 + ks * 4) ^ smswz)];
                acc0 = __builtin_amdgcn_mfma_f32_16x16x32_f16(wf[kk],     b0.h, acc0, 0, 0, 0);
                acc1 = __builtin_amdgcn_mfma_f32_16x16x32_f16(wf[kk + 1], b1.h, acc1, 0, 0, 0);
            }
        }

        // ---- in-lane gates + state update (lane owns i,f,g,o of its jj) ----
        {
            float xv = xsm[sm];
            float rb = (float)(w * 16 + ks * 4);   // row base for this lane
            int   r0 = w * 16 + ks * 4;
            float p0 = fmaf(xv, wih_s[r0 + 0], (acc0[0] + acc1[0]) + bsum_s[r0 + 0]);
            float p1 = fmaf(xv, wih_s[r0 + 1], (acc0[1] + acc1[1]) + bsum_s[r0 + 1]);
            float p2 = fmaf(xv, wih_s[r0 + 2], (acc0[2] + acc1[2]) + bsum_s[r0 + 2]);
            float p3 = fmaf(xv, wih_s[r0 + 3], (acc0[3] + acc1[3]) + bsum_s[r0 + 3]);
            (void)rb;
            float iv = 1.f / (1.f + __expf(-p0));
            float fv = 1.f / (1.f + __expf(-p1));
            float gv = 1.f - 2.f / (__expf(2.f * p2) + 1.f);
            float ov = 1.f / (1.f + __expf(-p3));
            float cn = fmaf(fv, creg, iv * gv);
            float hn = ov * (1.f - 2.f / (__expf(2.f * cn) + 1.f));
            bool  mk = mkm[sm] > 0.f;
            creg = mk ? cn : creg;
            hreg = mk ? hn : hreg;
            float* hout = hbuf + (size_t)((t + 1) & 1) * BB * HH;
            __hip_atomic_store(&hout[(size_t)sslot * HH + jg * JW + jj], hreg,
                               __ATOMIC_RELAXED, __HIP_MEMORY_SCOPE_AGENT);
        }
        __syncthreads();   // drains vmcnt: all h stores visible before flag

        if (tid == 0)
            __hip_atomic_store(&flg[jg * FS], t + 1, __ATOMIC_RELAXED,
                               __HIP_MEMORY_SCOPE_AGENT);

        if (t + 1 < glenA) {
            wait_flags(flg, t + 1, tid);
            // prefetch h(t+1) for both halves
            const float* hin = hbuf + (size_t)((t + 1) & 1) * BB * HH;
            const u64t* pA = (const u64t*)(hin + (size_t)(gA * SG + (tid >> 6)) * HH);
            const u64t* pB = (const u64t*)(hin + (size_t)(gB * SG + (tid >> 6)) * HH);
            #pragma unroll
            for (int q = 0; q < 4; ++q) {
                U64F va, vb;
                va.u = __hip_atomic_load(&pA[q * 64 + l], __ATOMIC_RELAXED,
                                         __HIP_MEMORY_SCOPE_AGENT);
                vb.u = __hip_atomic_load(&pB[q * 64 + l], __ATOMIC_RELAXED,
                                         __HIP_MEMORY_SCOPE_AGENT);
                pf[2 * q]     = va.f[0];
                pf[2 * q + 1] = va.f[1];
                pf[8 + 2 * q] = vb.f[0];
                pf[9 + 2 * q] = vb.f[1];
            }
        }
    }
}

// ---------------- epilogue: logits + masked softmax ----------------
__global__ __launch_bounds__(256) void epi_k(
    const float* __restrict__ hbuf, const float* __restrict__ fcWT,
    const float* __restrict__ fcb, const int* __restrict__ len,
    const int* __restrict__ perm, const int* __restrict__ glen,
    float* __restrict__ out)
{
    __shared__ float hb[HH];
    __shared__ float lg[TT];
    __shared__ float red[4];
    const int slot = blockIdx.x, tid = threadIdx.x;
    const int ob = perm[slot];
    const int g = slot >> 3;
    const int lead = (g < 16) ? g : (31 - g);     // pair leader sets iteration count
    const int par = glen[lead] & 1;

    const float* hfin = hbuf + ((size_t)par * BB + slot) * HH;
    for (int i = tid; i < HH; i += 256) hb[i] = hfin[i];
    __syncthreads();

    const int t0 = tid * 4;
    float a0 = fcb[t0], a1 = fcb[t0 + 1], a2 = fcb[t0 + 2], a3 = fcb[t0 + 3];
    #pragma unroll 8
    for (int k = 0; k < HH; ++k) {
        float4 w = *(const float4*)&fcWT[k * TT + t0];
        float hv = hb[k];
        a0 += w.x * hv; a1 += w.y * hv; a2 += w.z * hv; a3 += w.w * hv;
    }
    lg[t0] = a0; lg[t0 + 1] = a1; lg[t0 + 2] = a2; lg[t0 + 3] = a3;
    __syncthreads();

    const int L = len[ob];
    float mx = -3.4e38f;
    for (int i = tid; i < L; i += 256) mx = fmaxf(mx, lg[i]);
    for (int o = 32; o > 0; o >>= 1) mx = fmaxf(mx, __shfl_down(mx, o, 64));
    if ((tid & 63) == 0) red[tid >> 6] = mx;
    __syncthreads();
    mx = fmaxf(fmaxf(red[0], red[1]), fmaxf(red[2], red[3]));
    __syncthreads();

    float sm = 0.f;
    for (int i = tid; i < L; i += 256) {
        float e = __expf(lg[i] - mx);
        lg[i] = e;
        sm += e;
    }
    for (int o = 32; o > 0; o >>= 1) sm += __shfl_down(sm, o, 64);
    if ((tid & 63) == 0) red[tid >> 6] = sm;
    __syncthreads();
    sm = red[0] + red[1] + red[2] + red[3];
    float inv = 1.f / sm;

    for (int i = tid; i < TT; i += 256)
        out[ob * TT + i] = (i < L) ? lg[i] * inv : 1.0f;
}

// ---------------- launch ----------------
extern "C" void kernel_launch(void* const* d_in, const int* in_sizes, int n_in,
                              void* d_out, int out_size, void* d_ws, size_t ws_size,
                              hipStream_t stream)
{
    const float* traj = (const float*)d_in[0];
    const float* Wih  = (const float*)d_in[1];
    const float* Whh  = (const float*)d_in[2];
    const float* bih  = (const float*)d_in[3];
    const float* bhh  = (const float*)d_in[4];
    const float* fcW  = (const float*)d_in[5];
    const float* fcb  = (const float*)d_in[6];
    float* out = (float*)d_out;

    uint*  Wpk16 = (uint*)d_ws;                      // 524,288 dw (2MB)
    float* fcWT  = (float*)(Wpk16 + NJ * 8 * 16 * 64 * 4);  // 524,288
    float* bsum  = fcWT + HH * TT;                   // 2,048
    float* hbuf  = bsum + G4;                        // 2 * 131,072
    int*   len   = (int*)(hbuf + 2 * BB * HH);       // 256
    int*   perm  = len + BB;                         // 256
    int*   glen  = perm + BB;                        // 32
    int*   flags = glen + NG;                        // 32*16*32

    prep_k<<<2048, 256, 0, stream>>>(Whh, fcW, bih, bhh, Wpk16, fcWT, bsum, hbuf, flags);
    lens_k<<<BB, 256, 0, stream>>>(traj, len);
    sort_k<<<1, 256, 0, stream>>>(len, perm, glen);

    {
        const float* traj_l = traj; const float* wih_l = Wih;
        const uint* wpk_l = Wpk16;  const float* bsum_l = bsum;
        float* hbuf_l = hbuf;
        const int* perm_l = perm;   const int* glen_l = glen;
        int* flags_l = flags;
        void* args[] = { (void*)&traj_l, (void*)&wih_l, (void*)&wpk_l, (void*)&bsum_l,
                         (void*)&hbuf_l, (void*)&perm_l, (void*)&glen_l, (void*)&flags_l };
        (void)hipLaunchCooperativeKernel((const void*)lstm_persist, dim3(256), dim3(512),
                                         args, 0, stream);
    }

    epi_k<<<BB, 256, 0, stream>>>(hbuf, fcWT, fcb, len, perm, glen, out);
}

// Round 11
// 2607.802 us; speedup vs baseline: 1.1854x; 1.1854x over previous
//
#include <hip/hip_runtime.h>

#define TT 1024
#define BB 256
#define HH 512
#define G4 2048
#define NG 32   // sample groups
#define SG 8    // samples per group
#define NJ 16   // wgs (j-slices) per cohort
#define RW 128  // rows per slice = 4 gates * 32 j
#define JW 32   // j per slice
#define GXN 131072  // 2 * 256 * 256 exchange units (8B each)

typedef _Float16 half2v __attribute__((ext_vector_type(2)));
typedef _Float16 half8  __attribute__((ext_vector_type(8)));
typedef float    f32x4  __attribute__((ext_vector_type(4)));
typedef unsigned int uint;
typedef unsigned long long u64t;

union U32H  { uint u; half2v h; };
union U128H { uint4 u; half8 h; };

// ---------------- prep: fp16 W repack into MFMA A-fragments + gx tag clear --
// m = jjq*4 + gate (jj-major, gate-minor) so a lane's 4 D-regs are i,f,g,o of ONE jj.
__global__ __launch_bounds__(256) void prep_k(
    const float* __restrict__ Whh, const float* __restrict__ fcW,
    const float* __restrict__ bih, const float* __restrict__ bhh,
    uint* __restrict__ Wpk16, float* __restrict__ fcWT, float* __restrict__ bsum,
    u64t* __restrict__ gx)
{
    int n  = blockDim.x * gridDim.x;
    int i0 = blockIdx.x * blockDim.x + threadIdx.x;
    for (int i = i0; i < NJ * 8 * 16 * 64 * 4; i += n) {
        int d  = i & 3;
        int l  = (i >> 2) & 63;
        int kk = (i >> 8) & 15;
        int w  = (i >> 12) & 7;
        int jg = (i >> 15) & 15;
        int m    = l & 15;
        int gate = m & 3, jjq = m >> 2;
        int grow = gate * HH + jg * JW + w * 4 + jjq;
        int k    = kk * 32 + ((l >> 4) & 3) * 8 + 2 * d;
        half2v p;
        p.x = (_Float16)Whh[grow * HH + k];
        p.y = (_Float16)Whh[grow * HH + k + 1];
        U32H x; x.h = p;
        Wpk16[i] = x.u;
    }
    for (int i = i0; i < HH * TT; i += n) {
        int k = i >> 10, t = i & (TT - 1);
        fcWT[i] = fcW[t * HH + k];
    }
    for (int i = i0; i < G4; i += n) bsum[i] = bih[i] + bhh[i];
    for (int i = i0; i < GXN; i += n) gx[i] = 0;   // clear tags EVERY launch
}

// ---------------- lengths ----------------
__global__ __launch_bounds__(256) void lens_k(const float* __restrict__ traj,
                                              int* __restrict__ len)
{
    int b = blockIdx.x;
    int cnt = 0;
    for (int i = threadIdx.x; i < TT; i += 256)
        cnt += (traj[b * TT + i] != -1.0f) ? 1 : 0;
    for (int o = 32; o > 0; o >>= 1) cnt += __shfl_down(cnt, o, 64);
    __shared__ int s4[4];
    if ((threadIdx.x & 63) == 0) s4[threadIdx.x >> 6] = cnt;
    __syncthreads();
    if (threadIdx.x == 0) len[b] = s4[0] + s4[1] + s4[2] + s4[3];
}

// ---------------- sort by length (descending), group maxes ----------------
__global__ __launch_bounds__(256) void sort_k(const int* __restrict__ len,
                                              int* __restrict__ perm,
                                              int* __restrict__ glen)
{
    __shared__ int L[256];
    __shared__ int P[256];
    int tid = threadIdx.x;
    L[tid] = len[tid];
    __syncthreads();
    int l = L[tid], r = 0;
    for (int b = 0; b < 256; ++b) {
        int lb = L[b];
        r += (lb > l) || (lb == l && b < tid);
    }
    P[r] = tid;
    __syncthreads();
    perm[tid] = P[tid];
    if (tid < NG) glen[tid] = L[P[tid * SG]];
}

// ---------------- persistent LSTM: tagged-unit exchange (1-RT steady state) --
// grid 256 = 16 slots x 16 j-slices. Slot p serves groups gA=p (cols 0-7) and
// gB=31-p (cols 8-15) in one MFMA pass. Exchange: per (sample, dword-k2) unit
// {2 fp16 h | tag}, 8B agent atomics; consumers poll tags directly. No flags.
__global__ __launch_bounds__(512, 2) void lstm_persist(
    const float* __restrict__ traj, const float* __restrict__ Wih,
    const uint* __restrict__ Wpk16, const float* __restrict__ bsum,
    float* __restrict__ hbuf,                 // [BB][HH] final h only
    u64t* __restrict__ gx,                    // [2][256][256] tagged units
    const int* __restrict__ perm, const int* __restrict__ glen)
{
    __shared__ __align__(16) float smem[23040];   // 90KB -> 1 wg/CU
    __shared__ float xsm[16], mkm[16];
    __shared__ int   osm[16];
    __shared__ float wih_s[RW], bsum_s[RW];

    uint*     const hs16 = (uint*)smem;               // 16 x 256 dw
    _Float16* const pack = (_Float16*)(smem + 4096);  // [16][36] fp16

    const int wg   = blockIdx.x;
    const int slot = wg & 15;
    const int jg   = wg >> 4;
    const int tid  = threadIdx.x;
    const int gA = slot, gB = 31 - slot;

    if (tid < 16)
        osm[tid] = perm[(tid < 8) ? (gA * SG + tid) : (gB * SG + tid - 8)];
    if (tid < RW) {
        int m = tid & 15;
        int grow = (m & 3) * HH + jg * JW + (tid >> 4) * 4 + (m >> 2);
        wih_s[tid]  = Wih[grow];
        bsum_s[tid] = bsum[grow];
    }
    const int glenA = glen[gA];

    // W A-fragments -> registers
    half8 wf[16];
    {
        const int w0 = tid >> 6, l0 = tid & 63;
        const uint4* wp = (const uint4*)Wpk16;
        const int base = (jg * 8 + w0) * 1024 + l0;
        #pragma unroll
        for (int kk = 0; kk < 16; ++kk) {
            U128H u; u.u = wp[base + kk * 64];
            wf[kk] = u.h;
        }
    }

    // lane roles
    const int w   = tid >> 6;       // wave id: staging rows w, w+8; rows w*16..
    const int l   = tid & 63;
    const int sm  = l & 15;         // MFMA column = sample slot (A:0-7, B:8-15)
    const int ks  = (l >> 4) & 3;
    const int jjl = w * 4 + ks;     // lane's hidden index within slice (0..31)
    const int sslot = (sm < 8) ? (gA * SG + sm) : (gB * SG + sm - 8);
    const int csA = gA * SG + w;    // staging sample slots (consumer role)
    const int csB = gB * SG + w;
    const int swz = (w & 7) << 2;

    float creg = 0.f, hreg = 0.f;
    __syncthreads();

    for (int t = 0; t < glenA; ++t) {
        // ---- stage h(t) -> LDS (fp16 pairs, XOR-swizzled dword pairs) ----
        if (t == 0) {
            u64t z = 0;
            *(u64t*)&hs16[w * 256 + ((2 * l) ^ swz)]             = z;
            *(u64t*)&hs16[w * 256 + ((2 * l + 128) ^ swz)]       = z;
            *(u64t*)&hs16[(w + 8) * 256 + ((2 * l) ^ swz)]       = z;
            *(u64t*)&hs16[(w + 8) * 256 + ((2 * l + 128) ^ swz)] = z;
        } else {
            const u64t* base = gx + (size_t)(t & 1) * 65536;
            const u64t* pa = base + (size_t)csA * 256 + 2 * l;
            const u64t* pb = base + (size_t)csB * 256 + 2 * l;
            const uint tg = (uint)t;
            u64t v0, v1, v2, v3, v4, v5, v6, v7;
            int cap = 1 << 22;           // bounded spin: fail fast, never hang
            for (;;) {
                v0 = __hip_atomic_load(pa,       __ATOMIC_RELAXED, __HIP_MEMORY_SCOPE_AGENT);
                v1 = __hip_atomic_load(pa + 1,   __ATOMIC_RELAXED, __HIP_MEMORY_SCOPE_AGENT);
                v2 = __hip_atomic_load(pa + 128, __ATOMIC_RELAXED, __HIP_MEMORY_SCOPE_AGENT);
                v3 = __hip_atomic_load(pa + 129, __ATOMIC_RELAXED, __HIP_MEMORY_SCOPE_AGENT);
                v4 = __hip_atomic_load(pb,       __ATOMIC_RELAXED, __HIP_MEMORY_SCOPE_AGENT);
                v5 = __hip_atomic_load(pb + 1,   __ATOMIC_RELAXED, __HIP_MEMORY_SCOPE_AGENT);
                v6 = __hip_atomic_load(pb + 128, __ATOMIC_RELAXED, __HIP_MEMORY_SCOPE_AGENT);
                v7 = __hip_atomic_load(pb + 129, __ATOMIC_RELAXED, __HIP_MEMORY_SCOPE_AGENT);
                uint bad = ((uint)(v0 >> 32) ^ tg) | ((uint)(v1 >> 32) ^ tg)
                         | ((uint)(v2 >> 32) ^ tg) | ((uint)(v3 >> 32) ^ tg)
                         | ((uint)(v4 >> 32) ^ tg) | ((uint)(v5 >> 32) ^ tg)
                         | ((uint)(v6 >> 32) ^ tg) | ((uint)(v7 >> 32) ^ tg);
                if (!bad || --cap == 0) break;
                __builtin_amdgcn_s_sleep(1);
            }
            *(u64t*)&hs16[w * 256 + ((2 * l) ^ swz)]
                = (v0 & 0xffffffffull) | (v1 << 32);
            *(u64t*)&hs16[w * 256 + ((2 * l + 128) ^ swz)]
                = (v2 & 0xffffffffull) | (v3 << 32);
            *(u64t*)&hs16[(w + 8) * 256 + ((2 * l) ^ swz)]
                = (v4 & 0xffffffffull) | (v5 << 32);
            *(u64t*)&hs16[(w + 8) * 256 + ((2 * l + 128) ^ swz)]
                = (v6 & 0xffffffffull) | (v7 << 32);
        }
        if (tid < 16) {
            float v = traj[(size_t)osm[tid] * TT + t];
            xsm[tid] = v;
            mkm[tid] = (v != -1.0f) ? 1.f : 0.f;
        }
        __syncthreads();

        // ---- MFMA: 16 rows x 16 sample-columns, K=512, 2 acc chains ----
        f32x4 acc0 = {0.f, 0.f, 0.f, 0.f}, acc1 = {0.f, 0.f, 0.f, 0.f};
        {
            const int smswz = (sm & 7) << 2;
            const int bbase = sm * 256;
            #pragma unroll
            for (int kk = 0; kk < 16; kk += 2) {
                U128H b0, b1;
                b0.u = *(const uint4*)&hs16[bbase + ((kk * 16 + ks * 4) ^ smswz)];
                b1.u = *(const uint4*)&hs16[bbase + (((kk + 1) * 16 + ks * 4) ^ smswz)];
                acc0 = __builtin_amdgcn_mfma_f32_16x16x32_f16(wf[kk],     b0.h, acc0, 0, 0, 0);
                acc1 = __builtin_amdgcn_mfma_f32_16x16x32_f16(wf[kk + 1], b1.h, acc1, 0, 0, 0);
            }
        }

        // ---- in-lane gates + state update (lane owns i,f,g,o of its jj) ----
        {
            float xv = xsm[sm];
            int   r0 = w * 16 + ks * 4;
            float p0 = fmaf(xv, wih_s[r0 + 0], (acc0[0] + acc1[0]) + bsum_s[r0 + 0]);
            float p1 = fmaf(xv, wih_s[r0 + 1], (acc0[1] + acc1[1]) + bsum_s[r0 + 1]);
            float p2 = fmaf(xv, wih_s[r0 + 2], (acc0[2] + acc1[2]) + bsum_s[r0 + 2]);
            float p3 = fmaf(xv, wih_s[r0 + 3], (acc0[3] + acc1[3]) + bsum_s[r0 + 3]);
            float iv = 1.f / (1.f + __expf(-p0));
            float fv = 1.f / (1.f + __expf(-p1));
            float gv = 1.f - 2.f / (__expf(2.f * p2) + 1.f);
            float ov = 1.f / (1.f + __expf(-p3));
            float cn = fmaf(fv, creg, iv * gv);
            float hn = ov * (1.f - 2.f / (__expf(2.f * cn) + 1.f));
            bool  mk = mkm[sm] > 0.f;
            creg = mk ? cn : creg;
            hreg = mk ? hn : hreg;
            pack[sm * 36 + jjl] = (_Float16)hreg;
            if (t == glenA - 1)
                hbuf[(size_t)sslot * HH + jg * JW + jjl] = hreg;   // final h for epi
        }
        __syncthreads();   // pack visible to composer threads

        // ---- produce tagged units for h(t+1): one 8B agent store each ----
        if (t + 1 < glenA && tid < 256) {
            int s = tid >> 4, u = tid & 15;
            int k2 = jg * 16 + u;
            uint d = *(const uint*)&pack[s * 36 + u * 2];
            int ss = (s < 8) ? (gA * SG + s) : (gB * SG + s - 8);
            u64t val = (u64t)d | ((u64t)(uint)(t + 1) << 32);
            __hip_atomic_store(&gx[(size_t)((t + 1) & 1) * 65536 + (size_t)ss * 256 + k2],
                               val, __ATOMIC_RELAXED, __HIP_MEMORY_SCOPE_AGENT);
        }
    }
}

// ---------------- epilogue: logits + masked softmax ----------------
__global__ __launch_bounds__(256) void epi_k(
    const float* __restrict__ hbuf, const float* __restrict__ fcWT,
    const float* __restrict__ fcb, const int* __restrict__ len,
    const int* __restrict__ perm, float* __restrict__ out)
{
    __shared__ float hb[HH];
    __shared__ float lg[TT];
    __shared__ float red[4];
    const int slot = blockIdx.x, tid = threadIdx.x;
    const int ob = perm[slot];

    const float* hfin = hbuf + (size_t)slot * HH;
    for (int i = tid; i < HH; i += 256) hb[i] = hfin[i];
    __syncthreads();

    const int t0 = tid * 4;
    float a0 = fcb[t0], a1 = fcb[t0 + 1], a2 = fcb[t0 + 2], a3 = fcb[t0 + 3];
    #pragma unroll 8
    for (int k = 0; k < HH; ++k) {
        float4 w = *(const float4*)&fcWT[k * TT + t0];
        float hv = hb[k];
        a0 += w.x * hv; a1 += w.y * hv; a2 += w.z * hv; a3 += w.w * hv;
    }
    lg[t0] = a0; lg[t0 + 1] = a1; lg[t0 + 2] = a2; lg[t0 + 3] = a3;
    __syncthreads();

    const int L = len[ob];
    float mx = -3.4e38f;
    for (int i = tid; i < L; i += 256) mx = fmaxf(mx, lg[i]);
    for (int o = 32; o > 0; o >>= 1) mx = fmaxf(mx, __shfl_down(mx, o, 64));
    if ((tid & 63) == 0) red[tid >> 6] = mx;
    __syncthreads();
    mx = fmaxf(fmaxf(red[0], red[1]), fmaxf(red[2], red[3]));
    __syncthreads();

    float sm = 0.f;
    for (int i = tid; i < L; i += 256) {
        float e = __expf(lg[i] - mx);
        lg[i] = e;
        sm += e;
    }
    for (int o = 32; o > 0; o >>= 1) sm += __shfl_down(sm, o, 64);
    if ((tid & 63) == 0) red[tid >> 6] = sm;
    __syncthreads();
    sm = red[0] + red[1] + red[2] + red[3];
    float inv = 1.f / sm;

    for (int i = tid; i < TT; i += 256)
        out[ob * TT + i] = (i < L) ? lg[i] * inv : 1.0f;
}

// ---------------- launch ----------------
extern "C" void kernel_launch(void* const* d_in, const int* in_sizes, int n_in,
                              void* d_out, int out_size, void* d_ws, size_t ws_size,
                              hipStream_t stream)
{
    const float* traj = (const float*)d_in[0];
    const float* Wih  = (const float*)d_in[1];
    const float* Whh  = (const float*)d_in[2];
    const float* bih  = (const float*)d_in[3];
    const float* bhh  = (const float*)d_in[4];
    const float* fcW  = (const float*)d_in[5];
    const float* fcb  = (const float*)d_in[6];
    float* out = (float*)d_out;

    uint*  Wpk16 = (uint*)d_ws;                      // 524,288 dw (2MB)
    float* fcWT  = (float*)(Wpk16 + NJ * 8 * 16 * 64 * 4);  // 524,288 fl
    float* bsum  = fcWT + HH * TT;                   // 2,048
    float* hbuf  = bsum + G4;                        // 131,072 (final h)
    u64t*  gx    = (u64t*)(hbuf + BB * HH);          // 131,072 u64 (1MB)
    int*   len   = (int*)(gx + GXN);                 // 256
    int*   perm  = len + BB;                         // 256
    int*   glen  = perm + BB;                        // 32

    prep_k<<<2048, 256, 0, stream>>>(Whh, fcW, bih, bhh, Wpk16, fcWT, bsum, gx);
    lens_k<<<BB, 256, 0, stream>>>(traj, len);
    sort_k<<<1, 256, 0, stream>>>(len, perm, glen);

    {
        const float* traj_l = traj; const float* wih_l = Wih;
        const uint* wpk_l = Wpk16;  const float* bsum_l = bsum;
        float* hbuf_l = hbuf;       u64t* gx_l = gx;
        const int* perm_l = perm;   const int* glen_l = glen;
        void* args[] = { (void*)&traj_l, (void*)&wih_l, (void*)&wpk_l, (void*)&bsum_l,
                         (void*)&hbuf_l, (void*)&gx_l, (void*)&perm_l, (void*)&glen_l };
        (void)hipLaunchCooperativeKernel((const void*)lstm_persist, dim3(256), dim3(512),
                                         args, 0, stream);
    }

    epi_k<<<BB, 256, 0, stream>>>(hbuf, fcWT, fcb, len, perm, out);
}